// Round 2
// baseline (115.824 us; speedup 1.0000x reference)
//
#include <hip/hip_runtime.h>
#include <math.h>

namespace {
constexpr int kB  = 16;
constexpr int kNV = 6890;
constexpr int kNF = 13776;
constexpr int kP  = kB / 2;                       // 8 person-pairs
constexpr int kC  = 65536;                        // collisions per pair
constexpr int kNB = 256;                          // blocks (p = blk & 7 -> XCD-pinned)
constexpr int kTPB = 256;                         // 4 waves / block
constexpr int kWPB = kTPB / 64;
constexpr int kWavesPerPair = (kNB / kP) * kWPB;  // 128
constexpr int kLanesPerPair = kWavesPerPair * 64; // 8192
constexpr int kPasses = kC / kLanesPerPair;       // 8
}

#define SIGMA_F  1e-4f
#define EPS_F    1e-9f
#define THRESH_F 2000.0f
#define WEIGHT_F 0.1f

// Persistent device state, self-resetting each replay (last wave zeroes it).
__device__ int      g_flag[kP] = {};   // pair provably discarded (pen >= 2000)
__device__ float    g_pen[kP]  = {};   // per-pair accumulated pen
__device__ unsigned g_cnt[kP]  = {};   // waves finished per pair
__device__ unsigned g_done     = 0;    // pairs fully finished

// Exact reference-order cone distance field for one (receiver, intruder) pair.
__device__ __forceinline__ float cone_pair_loss(
    float3 r0, float3 r1, float3 r2, float3 i0, float3 i1, float3 i2) {
    float e1x = r1.x - r0.x, e1y = r1.y - r0.y, e1z = r1.z - r0.z;
    float e2x = r2.x - r0.x, e2y = r2.y - r0.y, e2z = r2.z - r0.z;
    float nx = e1y * e2z - e1z * e2y;
    float ny = e1z * e2x - e1x * e2z;
    float nz = e1x * e2y - e1y * e2x;
    float nn = sqrtf(nx * nx + ny * ny + nz * nz) + EPS_F;
    nx /= nn; ny /= nn; nz /= nn;
    float cx = (r0.x + r1.x + r2.x) / 3.0f;
    float cy = (r0.y + r1.y + r2.y) / 3.0f;
    float cz = (r0.z + r1.z + r2.z) / 3.0f;
    float r2m = 0.0f;
    {
        float dx = r0.x - cx, dy = r0.y - cy, dz = r0.z - cz;
        r2m = fmaxf(r2m, dx * dx + dy * dy + dz * dz);
        dx = r1.x - cx; dy = r1.y - cy; dz = r1.z - cz;
        r2m = fmaxf(r2m, dx * dx + dy * dy + dz * dz);
        dx = r2.x - cx; dy = r2.y - cy; dz = r2.z - cz;
        r2m = fmaxf(r2m, dx * dx + dy * dy + dz * dz);
    }
    float rad_eps = sqrtf(r2m) + EPS_F;
    float3 iv[3] = {i0, i1, i2};
    float acc = 0.0f;
#pragma unroll
    for (int k = 0; k < 3; ++k) {
        float dx = iv[k].x - cx, dy = iv[k].y - cy, dz = iv[k].z - cz;
        float d = dx * nx + dy * ny + dz * nz;
        float px = dx - d * nx, py = dy - d * ny, pz = dz - d * nz;
        float radial = sqrtf(px * px + py * py + pz * pz);
        float fa = fmaxf(-d / SIGMA_F, 0.0f);
        float fb = fmaxf(1.0f - radial / rad_eps, 0.0f);
        float fd = fa * fb;
        acc += fd * fd;
    }
    return acc;
}

// Direct gather + eval of one collision (branchless validity multiply so all
// scattered loads issue back-to-back).
__device__ __forceinline__ float eval_collision(
    int p, int2 idx,
    const float* __restrict__ verts, const int* __restrict__ faces,
    float t0x, float t0y, float t0z, float t1x, float t1y, float t1z) {
    int hi = (idx.x >= kNF) ? 1 : 0;
    int hr = (idx.y >= kNF) ? 1 : 0;
    const int* fi = faces + 3 * (idx.x - hi * kNF);
    const int* fr = faces + 3 * (idx.y - hr * kNF);
    int vi0 = fi[0], vi1 = fi[1], vi2 = fi[2];
    int vr0 = fr[0], vr1 = fr[1], vr2 = fr[2];
    size_t bi = (size_t)(2 * p + hi) * kNV;
    size_t br = (size_t)(2 * p + hr) * kNV;
    float tix = hi ? t1x : t0x, tiy = hi ? t1y : t0y, tiz = hi ? t1z : t0z;
    float trx = hr ? t1x : t0x, try_ = hr ? t1y : t0y, trz = hr ? t1z : t0z;
    const float* q;
    q = verts + (bi + vi0) * 3; float3 i0 = make_float3(q[0] + tix, q[1] + tiy, q[2] + tiz);
    q = verts + (bi + vi1) * 3; float3 i1 = make_float3(q[0] + tix, q[1] + tiy, q[2] + tiz);
    q = verts + (bi + vi2) * 3; float3 i2 = make_float3(q[0] + tix, q[1] + tiy, q[2] + tiz);
    q = verts + (br + vr0) * 3; float3 r0 = make_float3(q[0] + trx, q[1] + try_, q[2] + trz);
    q = verts + (br + vr1) * 3; float3 r1 = make_float3(q[0] + trx, q[1] + try_, q[2] + trz);
    q = verts + (br + vr2) * 3; float3 r2 = make_float3(q[0] + trx, q[1] + try_, q[2] + trz);
    float v = cone_pair_loss(r0, r1, r2, i0, i1, i2);
    return (idx.x != idx.y) ? v : 0.0f;
}

// Single fused kernel, fully wave-independent (no __syncthreads, no LDS).
//
// EXACT early exit: every pair_loss term is >= 0, so any partial sum >= 2000
// proves pen[p] >= 2000 => keep[p] = 0 => the pair contributes exactly 0.
// Each wave checks its own running sums (__any, one ballot) and a per-pair
// advisory flag (no spinning => deadlock-free at any occupancy/order).
//
// Completion: wave partial -> atomicAdd(g_pen[p]); acq_rel g_cnt[p] counts the
// pair's 128 waves; the pair-closer acq_rel-increments g_done; the wave seeing
// g_done==7 has a happens-before edge to every g_pen add (release-chain
// through g_cnt[p] then g_done) and finalizes + resets state for next replay.
__global__ void __launch_bounds__(256)
pen_fused(const int* __restrict__ coll,
          const float* __restrict__ verts,
          const float* __restrict__ trans,
          const int* __restrict__ faces,
          float* __restrict__ out) {
    const int blk  = blockIdx.x;
    const int p    = blk & 7;                         // XCD-pinned pair
    const int lane = threadIdx.x & 63;
    const int wq   = (blk >> 3) * kWPB + (threadIdx.x >> 6);  // 0..127 within pair
    const int2* cp = (const int2*)coll + (size_t)p * kC;

    const float t0x = trans[6 * p + 0], t0y = trans[6 * p + 1], t0z = trans[6 * p + 2];
    const float t1x = trans[6 * p + 3], t1y = trans[6 * p + 4], t1z = trans[6 * p + 5];

    float acc = 0.0f;
    for (int s = 0; s < kPasses; ++s) {
        int2 idx = cp[s * kLanesPerPair + wq * 64 + lane];
        acc += eval_collision(p, idx, verts, faces, t0x, t0y, t0z, t1x, t1y, t1z);
        if (__any(acc >= THRESH_F)) {       // wave-local exact proof of discard
            if (lane == 0)
                __hip_atomic_store(&g_flag[p], 1, __ATOMIC_RELAXED,
                                   __HIP_MEMORY_SCOPE_AGENT);
            break;
        }
        if (s + 1 < kPasses &&
            __hip_atomic_load(&g_flag[p], __ATOMIC_RELAXED,
                              __HIP_MEMORY_SCOPE_AGENT))
            break;                           // another wave proved it; stop
    }

    // wave-level partial (order within a wave is fixed)
#pragma unroll
    for (int off = 32; off > 0; off >>= 1)
        acc += __shfl_down(acc, off, 64);

    int fin = 0;
    if (lane == 0) {
        atomicAdd(&g_pen[p], acc);           // device-scope fp32 atomic
        unsigned o = __hip_atomic_fetch_add(&g_cnt[p], 1u, __ATOMIC_ACQ_REL,
                                            __HIP_MEMORY_SCOPE_AGENT);
        if (o == (unsigned)(kWavesPerPair - 1)) {       // pair-closer
            unsigned d = __hip_atomic_fetch_add(&g_done, 1u, __ATOMIC_ACQ_REL,
                                                __HIP_MEMORY_SCOPE_AGENT);
            fin = (d == (unsigned)(kP - 1));            // global-closer
        }
    }
    if (__shfl(fin, 0, 64) == 0) return;

    // ---- last wave, lane 0: finalize + reset persistent state ----
    if (lane == 0) {
        float cnt = 0.0f, vals = 0.0f;
#pragma unroll
        for (int e = 0; e < kP; ++e) {
            int fl = __hip_atomic_load(&g_flag[e], __ATOMIC_RELAXED,
                                       __HIP_MEMORY_SCOPE_AGENT);
            float pq = __hip_atomic_load(&g_pen[e], __ATOMIC_RELAXED,
                                         __HIP_MEMORY_SCOPE_AGENT);
            if (!fl && pq < THRESH_F) {      // NaN pen => excluded, matches jax
                cnt += 1.0f;
                vals += 1.0f / (1.0f + expf(-pq / THRESH_F)) - 0.5f;
            }
        }
        float loss = (cnt > 0.0f) ? (vals / fmaxf(cnt, 1.0f)) : 0.0f;
        out[0] = loss * WEIGHT_F;
        // reset for the next graph replay (stream-ordered => race-free)
#pragma unroll
        for (int e = 0; e < kP; ++e) {
            __hip_atomic_store(&g_flag[e], 0, __ATOMIC_RELAXED,
                               __HIP_MEMORY_SCOPE_AGENT);
            __hip_atomic_store(&g_pen[e], 0.0f, __ATOMIC_RELAXED,
                               __HIP_MEMORY_SCOPE_AGENT);
            __hip_atomic_store(&g_cnt[e], 0u, __ATOMIC_RELAXED,
                               __HIP_MEMORY_SCOPE_AGENT);
        }
        __hip_atomic_store(&g_done, 0u, __ATOMIC_RELEASE,
                           __HIP_MEMORY_SCOPE_AGENT);
    }
}

extern "C" void kernel_launch(void* const* d_in, const int* in_sizes, int n_in,
                              void* d_out, int out_size, void* d_ws, size_t ws_size,
                              hipStream_t stream) {
    const float* verts = (const float*)d_in[0];
    const float* trans = (const float*)d_in[1];
    const int*   faces = (const int*)d_in[2];
    const int*   coll  = (const int*)d_in[3];
    (void)d_ws; (void)ws_size; (void)in_sizes; (void)n_in; (void)out_size;
    pen_fused<<<kNB, kTPB, 0, stream>>>(coll, verts, trans, faces, (float*)d_out);
}

// Round 4
// 84.597 us; speedup vs baseline: 1.3691x; 1.3691x over previous
//
#include <hip/hip_runtime.h>
#include <math.h>

// Resubmit of R3 (container-level failure, no kernel signal): zero-RMW
// completion pipeline. See theory notes — R2's 70us pen_fused was same-line
// atomic-RMW coherence serialization; this version has no RMW atomics at all.

namespace {
constexpr int kB  = 16;
constexpr int kNV = 6890;
constexpr int kNF = 13776;
constexpr int kP  = kB / 2;                       // 8 person-pairs
constexpr int kC  = 65536;                        // collisions per pair
constexpr int kNB = 256;                          // blocks (p = blk & 7 -> XCD-pinned)
constexpr int kTPB = 256;                         // 4 waves / block
constexpr int kWPB = kTPB / 64;
constexpr int kBlocksPerPair = kNB / kP;          // 32
constexpr int kLanesPerPair  = kBlocksPerPair * kTPB;  // 8192
constexpr int kPasses = kC / kLanesPerPair;       // 8
}

#define SIGMA_F  1e-4f
#define EPS_F    1e-9f
#define THRESH_F 2000.0f
#define WEIGHT_F 0.1f

// Persistent device state.
//  g_flag: advisory "pair provably discarded" flags — set by store (never RMW),
//          polled with relaxed loads, reset by the finalize kernel each replay.
//  g_partials: one slot per block, unconditionally overwritten every replay
//          before finalize reads it => needs no reset. Plain stores only.
__device__ int   g_flag[kP] = {};
__device__ float g_partials[kNB];

// Exact reference-order cone distance field for one (receiver, intruder) pair.
__device__ __forceinline__ float cone_pair_loss(
    float3 r0, float3 r1, float3 r2, float3 i0, float3 i1, float3 i2) {
    float e1x = r1.x - r0.x, e1y = r1.y - r0.y, e1z = r1.z - r0.z;
    float e2x = r2.x - r0.x, e2y = r2.y - r0.y, e2z = r2.z - r0.z;
    float nx = e1y * e2z - e1z * e2y;
    float ny = e1z * e2x - e1x * e2z;
    float nz = e1x * e2y - e1y * e2x;
    float nn = sqrtf(nx * nx + ny * ny + nz * nz) + EPS_F;
    nx /= nn; ny /= nn; nz /= nn;
    float cx = (r0.x + r1.x + r2.x) / 3.0f;
    float cy = (r0.y + r1.y + r2.y) / 3.0f;
    float cz = (r0.z + r1.z + r2.z) / 3.0f;
    float r2m = 0.0f;
    {
        float dx = r0.x - cx, dy = r0.y - cy, dz = r0.z - cz;
        r2m = fmaxf(r2m, dx * dx + dy * dy + dz * dz);
        dx = r1.x - cx; dy = r1.y - cy; dz = r1.z - cz;
        r2m = fmaxf(r2m, dx * dx + dy * dy + dz * dz);
        dx = r2.x - cx; dy = r2.y - cy; dz = r2.z - cz;
        r2m = fmaxf(r2m, dx * dx + dy * dy + dz * dz);
    }
    float rad_eps = sqrtf(r2m) + EPS_F;
    float3 iv[3] = {i0, i1, i2};
    float acc = 0.0f;
#pragma unroll
    for (int k = 0; k < 3; ++k) {
        float dx = iv[k].x - cx, dy = iv[k].y - cy, dz = iv[k].z - cz;
        float d = dx * nx + dy * ny + dz * nz;
        float px = dx - d * nx, py = dy - d * ny, pz = dz - d * nz;
        float radial = sqrtf(px * px + py * py + pz * pz);
        float fa = fmaxf(-d / SIGMA_F, 0.0f);
        float fb = fmaxf(1.0f - radial / rad_eps, 0.0f);
        float fd = fa * fb;
        acc += fd * fd;
    }
    return acc;
}

// Direct gather + eval of one collision (branchless validity multiply so all
// scattered loads issue back-to-back).
__device__ __forceinline__ float eval_collision(
    int p, int2 idx,
    const float* __restrict__ verts, const int* __restrict__ faces,
    float t0x, float t0y, float t0z, float t1x, float t1y, float t1z) {
    int hi = (idx.x >= kNF) ? 1 : 0;
    int hr = (idx.y >= kNF) ? 1 : 0;
    const int* fi = faces + 3 * (idx.x - hi * kNF);
    const int* fr = faces + 3 * (idx.y - hr * kNF);
    int vi0 = fi[0], vi1 = fi[1], vi2 = fi[2];
    int vr0 = fr[0], vr1 = fr[1], vr2 = fr[2];
    size_t bi = (size_t)(2 * p + hi) * kNV;
    size_t br = (size_t)(2 * p + hr) * kNV;
    float tix = hi ? t1x : t0x, tiy = hi ? t1y : t0y, tiz = hi ? t1z : t0z;
    float trx = hr ? t1x : t0x, try_ = hr ? t1y : t0y, trz = hr ? t1z : t0z;
    const float* q;
    q = verts + (bi + vi0) * 3; float3 i0 = make_float3(q[0] + tix, q[1] + tiy, q[2] + tiz);
    q = verts + (bi + vi1) * 3; float3 i1 = make_float3(q[0] + tix, q[1] + tiy, q[2] + tiz);
    q = verts + (bi + vi2) * 3; float3 i2 = make_float3(q[0] + tix, q[1] + tiy, q[2] + tiz);
    q = verts + (br + vr0) * 3; float3 r0 = make_float3(q[0] + trx, q[1] + try_, q[2] + trz);
    q = verts + (br + vr1) * 3; float3 r1 = make_float3(q[0] + trx, q[1] + try_, q[2] + trz);
    q = verts + (br + vr2) * 3; float3 r2 = make_float3(q[0] + trx, q[1] + try_, q[2] + trz);
    float v = cone_pair_loss(r0, r1, r2, i0, i1, i2);
    return (idx.x != idx.y) ? v : 0.0f;
}

// Pass loop is wave-independent (no barriers, no LDS, no RMW atomics).
//
// EXACT early exit: every pair_loss term is >= 0, so any partial sum >= 2000
// proves pen[p] >= 2000 => keep[p] = 0 => the pair contributes exactly 0.
// The flag is advisory (store-only set + relaxed polls, no spinning), so the
// kernel is deadlock-free at any occupancy/dispatch order, and the output is
// input-deterministic: a wave that would trigger the flag does so
// deterministically unless the pair is already proven discarded.
__global__ void __launch_bounds__(256)
pen_fused(const int* __restrict__ coll,
          const float* __restrict__ verts,
          const float* __restrict__ trans,
          const int* __restrict__ faces) {
    const int blk  = blockIdx.x;
    const int p    = blk & 7;                          // XCD-pinned pair
    const int lane = threadIdx.x & 63;
    const int wid  = threadIdx.x >> 6;
    const int2* cp = (const int2*)coll + (size_t)p * kC
                   + (size_t)(blk >> 3) * (kPasses * kTPB);

    const float t0x = trans[6 * p + 0], t0y = trans[6 * p + 1], t0z = trans[6 * p + 2];
    const float t1x = trans[6 * p + 3], t1y = trans[6 * p + 4], t1z = trans[6 * p + 5];

    float acc = 0.0f;
    for (int s = 0; s < kPasses; ++s) {
        int2 idx = cp[s * kTPB + threadIdx.x];
        acc += eval_collision(p, idx, verts, faces, t0x, t0y, t0z, t1x, t1y, t1z);
        if (__any(acc >= THRESH_F)) {        // wave-local exact proof of discard
            if (lane == 0)
                __hip_atomic_store(&g_flag[p], 1, __ATOMIC_RELAXED,
                                   __HIP_MEMORY_SCOPE_AGENT);
            break;
        }
        if (s + 1 < kPasses &&
            __hip_atomic_load(&g_flag[p], __ATOMIC_RELAXED,
                              __HIP_MEMORY_SCOPE_AGENT))
            break;                            // another wave proved it; stop
    }

    // block partial: wave shuffle reduce -> LDS -> single plain store.
#pragma unroll
    for (int off = 32; off > 0; off >>= 1)
        acc += __shfl_down(acc, off, 64);
    __shared__ float red[kWPB];
    if (lane == 0) red[wid] = acc;
    __syncthreads();
    if (threadIdx.x == 0)
        g_partials[blk] = red[0] + red[1] + red[2] + red[3];
}

// 1 block, 512 threads = 8 waves; wave w reduces pair w's 32 partials.
// Also resets g_flag for the next graph replay (stream-ordered => race-free).
__global__ void __launch_bounds__(512)
finalize_kernel(float* __restrict__ out) {
    const int wv   = threadIdx.x >> 6;   // pair 0..7
    const int lane = threadIdx.x & 63;
    float s = 0.0f;
    for (int j = lane; j < kBlocksPerPair; j += 64)   // lanes 0..31 load
        s += g_partials[wv + 8 * j];
#pragma unroll
    for (int off = 32; off > 0; off >>= 1)
        s += __shfl_down(s, off, 64);
    __shared__ float pen[kP];
    if (lane == 0) pen[wv] = s;
    __syncthreads();
    if (threadIdx.x == 0) {
        float cnt = 0.0f, vals = 0.0f;
#pragma unroll
        for (int e = 0; e < kP; ++e) {
            int fl = __hip_atomic_load(&g_flag[e], __ATOMIC_RELAXED,
                                       __HIP_MEMORY_SCOPE_AGENT);
            float pq = pen[e];
            if (!fl && pq < THRESH_F) {      // NaN pen => excluded
                cnt += 1.0f;
                vals += 1.0f / (1.0f + expf(-pq / THRESH_F)) - 0.5f;
            }
        }
        float loss = (cnt > 0.0f) ? (vals / fmaxf(cnt, 1.0f)) : 0.0f;
        out[0] = loss * WEIGHT_F;
        // reset flags for the next replay (plain stores, no contention)
#pragma unroll
        for (int e = 0; e < kP; ++e)
            __hip_atomic_store(&g_flag[e], 0, __ATOMIC_RELAXED,
                               __HIP_MEMORY_SCOPE_AGENT);
    }
}

extern "C" void kernel_launch(void* const* d_in, const int* in_sizes, int n_in,
                              void* d_out, int out_size, void* d_ws, size_t ws_size,
                              hipStream_t stream) {
    const float* verts = (const float*)d_in[0];
    const float* trans = (const float*)d_in[1];
    const int*   faces = (const int*)d_in[2];
    const int*   coll  = (const int*)d_in[3];
    (void)d_ws; (void)ws_size; (void)in_sizes; (void)n_in; (void)out_size;
    pen_fused<<<kNB, kTPB, 0, stream>>>(coll, verts, trans, faces);
    finalize_kernel<<<1, 512, 0, stream>>>((float*)d_out);
}

// Round 5
// 65.162 us; speedup vs baseline: 1.7775x; 1.2983x over previous
//
#include <hip/hip_runtime.h>
#include <math.h>

// R5: zero-communication early exit. Key invariant: fp32 addition of
// non-negatives is monotone, so a wave that exits because some lane's running
// sum >= 2000 necessarily publishes a wave partial >= 2000; the pair's summed
// partials then fail finalize's `pen < 2000` keep-test — the same exact
// discard the reference computes. No flags, no atomics, no RMWs anywhere.

namespace {
constexpr int kNV = 6890;
constexpr int kNF = 13776;
constexpr int kP  = 8;                            // person-pairs
constexpr int kC  = 65536;                        // collisions per pair
constexpr int kNB = 256;                          // blocks (p = blk & 7 -> XCD-pinned)
constexpr int kTPB = 256;                         // 4 waves / block
constexpr int kWPB = kTPB / 64;
constexpr int kBlocksPerPair = kNB / kP;          // 32
constexpr int kPasses = kC / (kBlocksPerPair * kTPB);  // 8
}

#define SIGMA_F  1e-4f
#define EPS_F    1e-9f
#define THRESH_F 2000.0f
#define WEIGHT_F 0.1f

// One slot per block; unconditionally overwritten every replay before being
// read => needs no reset. Plain stores only; cross-dispatch visibility is
// guaranteed by same-stream kernel ordering.
__device__ float g_partials[kNB];

// Exact reference-order cone distance field for one (receiver, intruder) pair.
__device__ __forceinline__ float cone_pair_loss(
    float3 r0, float3 r1, float3 r2, float3 i0, float3 i1, float3 i2) {
    float e1x = r1.x - r0.x, e1y = r1.y - r0.y, e1z = r1.z - r0.z;
    float e2x = r2.x - r0.x, e2y = r2.y - r0.y, e2z = r2.z - r0.z;
    float nx = e1y * e2z - e1z * e2y;
    float ny = e1z * e2x - e1x * e2z;
    float nz = e1x * e2y - e1y * e2x;
    float nn = sqrtf(nx * nx + ny * ny + nz * nz) + EPS_F;
    nx /= nn; ny /= nn; nz /= nn;
    float cx = (r0.x + r1.x + r2.x) / 3.0f;
    float cy = (r0.y + r1.y + r2.y) / 3.0f;
    float cz = (r0.z + r1.z + r2.z) / 3.0f;
    float r2m = 0.0f;
    {
        float dx = r0.x - cx, dy = r0.y - cy, dz = r0.z - cz;
        r2m = fmaxf(r2m, dx * dx + dy * dy + dz * dz);
        dx = r1.x - cx; dy = r1.y - cy; dz = r1.z - cz;
        r2m = fmaxf(r2m, dx * dx + dy * dy + dz * dz);
        dx = r2.x - cx; dy = r2.y - cy; dz = r2.z - cz;
        r2m = fmaxf(r2m, dx * dx + dy * dy + dz * dz);
    }
    float rad_eps = sqrtf(r2m) + EPS_F;
    float3 iv[3] = {i0, i1, i2};
    float acc = 0.0f;
#pragma unroll
    for (int k = 0; k < 3; ++k) {
        float dx = iv[k].x - cx, dy = iv[k].y - cy, dz = iv[k].z - cz;
        float d = dx * nx + dy * ny + dz * nz;
        float px = dx - d * nx, py = dy - d * ny, pz = dz - d * nz;
        float radial = sqrtf(px * px + py * py + pz * pz);
        float fa = fmaxf(-d / SIGMA_F, 0.0f);
        float fb = fmaxf(1.0f - radial / rad_eps, 0.0f);
        float fd = fa * fb;
        acc += fd * fd;
    }
    return acc;
}

// Direct gather + eval of one collision (branchless validity multiply so all
// scattered loads issue back-to-back).
__device__ __forceinline__ float eval_collision(
    int p, int2 idx,
    const float* __restrict__ verts, const int* __restrict__ faces,
    float t0x, float t0y, float t0z, float t1x, float t1y, float t1z) {
    int hi = (idx.x >= kNF) ? 1 : 0;
    int hr = (idx.y >= kNF) ? 1 : 0;
    const int* fi = faces + 3 * (idx.x - hi * kNF);
    const int* fr = faces + 3 * (idx.y - hr * kNF);
    int vi0 = fi[0], vi1 = fi[1], vi2 = fi[2];
    int vr0 = fr[0], vr1 = fr[1], vr2 = fr[2];
    size_t bi = (size_t)(2 * p + hi) * kNV;
    size_t br = (size_t)(2 * p + hr) * kNV;
    float tix = hi ? t1x : t0x, tiy = hi ? t1y : t0y, tiz = hi ? t1z : t0z;
    float trx = hr ? t1x : t0x, try_ = hr ? t1y : t0y, trz = hr ? t1z : t0z;
    const float* q;
    q = verts + (bi + vi0) * 3; float3 i0 = make_float3(q[0] + tix, q[1] + tiy, q[2] + tiz);
    q = verts + (bi + vi1) * 3; float3 i1 = make_float3(q[0] + tix, q[1] + tiy, q[2] + tiz);
    q = verts + (bi + vi2) * 3; float3 i2 = make_float3(q[0] + tix, q[1] + tiy, q[2] + tiz);
    q = verts + (br + vr0) * 3; float3 r0 = make_float3(q[0] + trx, q[1] + try_, q[2] + trz);
    q = verts + (br + vr1) * 3; float3 r1 = make_float3(q[0] + trx, q[1] + try_, q[2] + trz);
    q = verts + (br + vr2) * 3; float3 r2 = make_float3(q[0] + trx, q[1] + try_, q[2] + trz);
    float v = cone_pair_loss(r0, r1, r2, i0, i1, i2);
    return (idx.x != idx.y) ? v : 0.0f;
}

// Pass loop: wave-local exact early exit (ballot only). Block-local advisory
// hint via volatile LDS (CU-local, no coherence traffic) bounds the tail for
// waves that never self-trigger. No global communication of any kind.
__global__ void __launch_bounds__(256)
pen_kernel(const int* __restrict__ coll,
           const float* __restrict__ verts,
           const float* __restrict__ trans,
           const int* __restrict__ faces) {
    const int blk  = blockIdx.x;
    const int p    = blk & 7;                          // XCD-pinned pair
    const int lane = threadIdx.x & 63;
    const int wid  = threadIdx.x >> 6;
    const int2* cp = (const int2*)coll + (size_t)p * kC
                   + (size_t)(blk >> 3) * (kPasses * kTPB);

    const float t0x = trans[6 * p + 0], t0y = trans[6 * p + 1], t0z = trans[6 * p + 2];
    const float t1x = trans[6 * p + 3], t1y = trans[6 * p + 4], t1z = trans[6 * p + 5];

    volatile __shared__ int s_exit;
    if (threadIdx.x == 0) s_exit = 0;
    __syncthreads();

    float acc = 0.0f;
    for (int s = 0; s < kPasses; ++s) {
        int2 idx = cp[s * kTPB + threadIdx.x];
        acc += eval_collision(p, idx, verts, faces, t0x, t0y, t0z, t1x, t1y, t1z);
        if (__any(acc >= THRESH_F)) {
            // this wave's partial is already >= 2000 => pair provably discarded
            if (lane == 0) s_exit = 1;      // CU-local hint for sibling waves
            break;
        }
        if (s + 1 < kPasses && s_exit) break;  // advisory; benign race
    }

    // wave reduce -> LDS -> one plain store per block
#pragma unroll
    for (int off = 32; off > 0; off >>= 1)
        acc += __shfl_down(acc, off, 64);
    __shared__ float red[kWPB];
    if (lane == 0) red[wid] = acc;
    __syncthreads();
    if (threadIdx.x == 0)
        g_partials[blk] = red[0] + red[1] + red[2] + red[3];
}

// 1 block, 512 threads = 8 waves; wave w reduces pair w's 32 partials.
__global__ void __launch_bounds__(512)
finalize_kernel(float* __restrict__ out) {
    const int wv   = threadIdx.x >> 6;   // pair 0..7
    const int lane = threadIdx.x & 63;
    float s = 0.0f;
    for (int j = lane; j < kBlocksPerPair; j += 64)   // lanes 0..31 load
        s += g_partials[wv + 8 * j];
#pragma unroll
    for (int off = 32; off > 0; off >>= 1)
        s += __shfl_down(s, off, 64);
    __shared__ float pen[kP];
    if (lane == 0) pen[wv] = s;
    __syncthreads();
    if (threadIdx.x == 0) {
        float cnt = 0.0f, vals = 0.0f;
#pragma unroll
        for (int e = 0; e < kP; ++e) {
            float pq = pen[e];
            if (pq < THRESH_F) {             // NaN pen => excluded, matches jax
                cnt += 1.0f;
                vals += 1.0f / (1.0f + expf(-pq / THRESH_F)) - 0.5f;
            }
        }
        float loss = (cnt > 0.0f) ? (vals / fmaxf(cnt, 1.0f)) : 0.0f;
        out[0] = loss * WEIGHT_F;
    }
}

extern "C" void kernel_launch(void* const* d_in, const int* in_sizes, int n_in,
                              void* d_out, int out_size, void* d_ws, size_t ws_size,
                              hipStream_t stream) {
    const float* verts = (const float*)d_in[0];
    const float* trans = (const float*)d_in[1];
    const int*   faces = (const int*)d_in[2];
    const int*   coll  = (const int*)d_in[3];
    (void)d_ws; (void)ws_size; (void)in_sizes; (void)n_in; (void)out_size;
    pen_kernel<<<kNB, kTPB, 0, stream>>>(coll, verts, trans, faces);
    finalize_kernel<<<1, 512, 0, stream>>>((float*)d_out);
}